// Round 3
// baseline (1314.712 us; speedup 1.0000x reference)
//
#include <hip/hip_runtime.h>
#include <math.h>

#define NN 100000
#define NE 1600000
#define NB 782      // dst buckets of 128 nodes
#define BCAP 3072   // bucket capacity (mean ~2046, binomial tail safe)

typedef unsigned short ushort_t;
typedef unsigned int uint_t;
typedef __attribute__((ext_vector_type(8))) short bf16x8;
typedef __attribute__((ext_vector_type(8))) unsigned short u16x8;
typedef __attribute__((ext_vector_type(4))) float f32x4;

__device__ __forceinline__ ushort_t f2bf(float f) {
  uint_t u = __float_as_uint(f);
  u = (u + 0x7fffu + ((u >> 16) & 1u)) >> 16;   // round-to-nearest-even
  return (ushort_t)u;
}
__device__ __forceinline__ float bf2f(ushort_t h) {
  return __uint_as_float((uint_t)h << 16);
}

// ---------------- setup: bucketed CSR build ----------------

__global__ __launch_bounds__(256) void bucket_k(const int* __restrict__ src, const int* __restrict__ dst,
                                                int* __restrict__ bcnt, uint_t* __restrict__ pairs) {
  int e = blockIdx.x * 256 + threadIdx.x;
  if (e < NE) {
    int s = src[e], d = dst[e];
    int b = d >> 7;
    int pos = atomicAdd(&bcnt[b], 1);
    if (pos < BCAP) pairs[b * BCAP + pos] = ((uint_t)s << 7) | (uint_t)(d & 127);
  }
}

__global__ __launch_bounds__(256) void count2_k(const int* __restrict__ bcnt, const uint_t* __restrict__ pairs,
                                                int* __restrict__ cnt) {
  __shared__ int c[128];
  int b = blockIdx.x, t = threadIdx.x;
  if (t < 128) c[t] = 0;
  __syncthreads();
  int n = min(bcnt[b], BCAP);
  for (int i = t; i < n; i += 256) atomicAdd(&c[pairs[b * BCAP + i] & 127], 1);
  __syncthreads();
  if (t < 128) {
    int node = b * 128 + t;
    if (node < NN) cnt[node] = c[t];
  }
}

__global__ __launch_bounds__(256) void dinv_k(const int* __restrict__ cnt, float* __restrict__ dinv) {
  int i = blockIdx.x * 256 + threadIdx.x;
  if (i < NN) dinv[i] = rsqrtf((float)(cnt[i] + 1));  // +1 self-loop; always > 0
}

__global__ __launch_bounds__(1024) void scan1(const int* __restrict__ cnt, int* __restrict__ rowstart,
                                              int* __restrict__ blocksum) {
  __shared__ int s[1024];
  int t = threadIdx.x;
  int i = blockIdx.x * 1024 + t;
  int v = (i < NN) ? cnt[i] : 0;
  s[t] = v;
  __syncthreads();
  for (int off = 1; off < 1024; off <<= 1) {
    int add = (t >= off) ? s[t - off] : 0;
    __syncthreads();
    s[t] += add;
    __syncthreads();
  }
  if (i < NN) rowstart[i] = s[t] - v;   // exclusive
  if (t == 1023) blocksum[blockIdx.x] = s[1023];
}

__global__ void scan2(int* blocksum, int nb) {
  if (threadIdx.x == 0 && blockIdx.x == 0) {
    int acc = 0;
    for (int b = 0; b < nb; ++b) { int v = blocksum[b]; blocksum[b] = acc; acc += v; }
  }
}

__global__ __launch_bounds__(1024) void scan3(int* __restrict__ rowstart, const int* __restrict__ blocksum) {
  int i = blockIdx.x * 1024 + threadIdx.x;
  if (i < NN) rowstart[i] += blocksum[blockIdx.x];
}

__global__ __launch_bounds__(256) void fill2_k(const int* __restrict__ bcnt, const uint_t* __restrict__ pairs,
                                               const int* __restrict__ rowstart, int* __restrict__ csr) {
  __shared__ int cur[128];
  int b = blockIdx.x, t = threadIdx.x;
  if (t < 128) cur[t] = 0;
  __syncthreads();
  int n = min(bcnt[b], BCAP);
  for (int i = t; i < n; i += 256) {
    uint_t p = pairs[b * BCAP + i];
    int lo = p & 127;
    int pos = rowstart[b * 128 + lo] + atomicAdd(&cur[lo], 1);
    csr[pos] = (int)(p >> 7);
  }
}

// ---------------- weight prep: transpose + bf16 hi/lo split ----------------
// Wt[n][k] (k-contiguous) so B-fragments are 16B LDS reads.

__global__ __launch_bounds__(256) void wprep_k(const float* __restrict__ Wg1, const float* __restrict__ Wg2,
                                               const float* __restrict__ Wl,
                                               ushort_t* __restrict__ G1h, ushort_t* __restrict__ G1l,
                                               ushort_t* __restrict__ G2h, ushort_t* __restrict__ G2l,
                                               ushort_t* __restrict__ Lh, ushort_t* __restrict__ Ll) {
  int i = blockIdx.x * 256 + threadIdx.x;   // 0..73727
  float w;
  ushort_t *ph, *pl;
  size_t di;
  if (i < 16384) {           // Wg1 128x128
    int k = i >> 7, n = i & 127;
    w = Wg1[i]; di = (size_t)n * 128 + k; ph = G1h; pl = G1l;
  } else if (i < 32768) {    // Wg2 128x128
    int i2 = i - 16384;
    int k = i2 >> 7, n = i2 & 127;
    w = Wg2[i2]; di = (size_t)n * 128 + k; ph = G2h; pl = G2l;
  } else {                   // Wl 10 x 64x64
    int i2 = i - 32768;
    int j = i2 >> 12, r = i2 & 4095;
    int k = r >> 6, n = r & 63;
    w = Wl[i2]; di = (size_t)j * 4096 + n * 64 + k; ph = Lh; pl = Ll;
  }
  ushort_t h = f2bf(w);
  ph[di] = h;
  pl[di] = f2bf(w - bf2f(h));
}

// ---------------- MFMA GEMM (bf16x3 split ~ f32 accuracy) ----------------
// C[i,n] = bf16( dinv[i] * sum_k A[i,k] W[k,n] ).  64 rows/block, 4 waves,
// wave w: rows w*16..+15, all DC cols. K chunked by 64.

template <int K, int DC>
__global__ __launch_bounds__(256) void mgemm_k(const float* __restrict__ A,
                                               const ushort_t* __restrict__ Wth, const ushort_t* __restrict__ Wtl,
                                               const float* __restrict__ dinv, ushort_t* __restrict__ C) {
  constexpr int NCH = K / 64;
  __shared__ ushort_t Ah[64 * 64], Al[64 * 64];
  __shared__ ushort_t Wh[DC * 64], Wl_[DC * 64];
  const int t = threadIdx.x;
  const int row0 = blockIdx.x * 64;
  const int w = t >> 6, l = t & 63;
  const int lr = l & 15, kh = l >> 4;

  f32x4 acc[DC / 16];
  const f32x4 zz = {0.f, 0.f, 0.f, 0.f};
#pragma unroll
  for (int ct = 0; ct < DC / 16; ++ct) acc[ct] = zz;

  for (int kc = 0; kc < NCH; ++kc) {
    if (kc) __syncthreads();
    // stage A chunk (64 rows x 64 k), f32 -> bf16 hi/lo, XOR-swizzled
#pragma unroll
    for (int it = 0; it < 4; ++it) {
      int idx = t + it * 256;
      int row = idx >> 4, kq = idx & 15;
      int gr = min(row0 + row, NN - 1);
      float4 a = *(const float4*)&A[(size_t)gr * K + kc * 64 + kq * 4];
      ushort4 h, lo;
      h.x = f2bf(a.x); lo.x = f2bf(a.x - bf2f(h.x));
      h.y = f2bf(a.y); lo.y = f2bf(a.y - bf2f(h.y));
      h.z = f2bf(a.z); lo.z = f2bf(a.z - bf2f(h.z));
      h.w = f2bf(a.w); lo.w = f2bf(a.w - bf2f(h.w));
      int byt = (row * 128 + kq * 8) ^ ((row & 7) << 4);
      *(ushort4*)&Ah[byt >> 1] = h;
      *(ushort4*)&Al[byt >> 1] = lo;
    }
    // stage W chunk (DC cols x 64 k), pre-split bf16, XOR-swizzled
    for (int idx = t; idx < DC * 8; idx += 256) {
      int n = idx >> 3, kq = idx & 7;
      u16x8 hv = *(const u16x8*)&Wth[(size_t)n * K + kc * 64 + kq * 8];
      u16x8 lv = *(const u16x8*)&Wtl[(size_t)n * K + kc * 64 + kq * 8];
      int byt = (n * 128 + kq * 16) ^ ((n & 7) << 4);
      *(u16x8*)&Wh[byt >> 1] = hv;
      *(u16x8*)&Wl_[byt >> 1] = lv;
    }
    __syncthreads();
    // compute: 2 k-halves of 32, bf16x3: Al*Wh + Ah*Wl + Ah*Wh
#pragma unroll
    for (int kc2 = 0; kc2 < 2; ++kc2) {
      int arow = w * 16 + lr;
      int ab = (arow * 128 + kc2 * 64 + kh * 16) ^ ((arow & 7) << 4);
      bf16x8 ah = *(const bf16x8*)&Ah[ab >> 1];
      bf16x8 al = *(const bf16x8*)&Al[ab >> 1];
#pragma unroll
      for (int ct = 0; ct < DC / 16; ++ct) {
        int n = ct * 16 + lr;
        int bb = (n * 128 + kc2 * 64 + kh * 16) ^ ((n & 7) << 4);
        bf16x8 bh = *(const bf16x8*)&Wh[bb >> 1];
        bf16x8 bl = *(const bf16x8*)&Wl_[bb >> 1];
        acc[ct] = __builtin_amdgcn_mfma_f32_16x16x32_bf16(al, bh, acc[ct], 0, 0, 0);
        acc[ct] = __builtin_amdgcn_mfma_f32_16x16x32_bf16(ah, bl, acc[ct], 0, 0, 0);
        acc[ct] = __builtin_amdgcn_mfma_f32_16x16x32_bf16(ah, bh, acc[ct], 0, 0, 0);
      }
    }
  }
  // epilogue: C/D layout col=lane&15, row=(lane>>4)*4+reg
  float dv[4];
#pragma unroll
  for (int r = 0; r < 4; ++r) {
    int grow = row0 + w * 16 + kh * 4 + r;
    dv[r] = (grow < NN) ? dinv[grow] : 0.0f;
  }
#pragma unroll
  for (int ct = 0; ct < DC / 16; ++ct) {
    int col = ct * 16 + lr;
#pragma unroll
    for (int r = 0; r < 4; ++r) {
      int grow = row0 + w * 16 + kh * 4 + r;
      if (grow < NN) C[(size_t)grow * DC + col] = f2bf(acc[ct][r] * dv[r]);
    }
  }
}

// ---------------- f32 VALU GEMM (head only) ----------------

template <int K1, int K2, int DC, int ROWS, int ACT, bool PRESCALE, bool BIAS>
__global__ __launch_bounds__(256) void gemm_k(const float* __restrict__ A1, const float* __restrict__ A2,
                                              const float* __restrict__ W, const float* __restrict__ bias,
                                              const float* __restrict__ dinv, float* __restrict__ C) {
  constexpr int K = K1 + K2;
  static_assert((DC / 4) * (ROWS / 4) == 256, "thread map");
  __shared__ float Ws[K * DC];
  __shared__ float Xs[K * ROWS];
  const int tid = threadIdx.x;
  const int row0 = blockIdx.x * ROWS;

  for (int idx = tid * 4; idx < K * DC; idx += 1024)
    *(float4*)&Ws[idx] = *(const float4*)&W[idx];

  for (int idx = tid; idx < K * (ROWS / 4); idx += 256) {
    int k = idx % K;
    int r0 = (idx / K) * 4;
    int g0 = row0 + r0;
    int gr0 = min(g0 + 0, NN - 1);
    int gr1 = min(g0 + 1, NN - 1);
    int gr2 = min(g0 + 2, NN - 1);
    int gr3 = min(g0 + 3, NN - 1);
    float4 v;
    if constexpr (K2 > 0) {
      if (k < K1) {
        v.x = A1[(size_t)gr0 * K1 + k]; v.y = A1[(size_t)gr1 * K1 + k];
        v.z = A1[(size_t)gr2 * K1 + k]; v.w = A1[(size_t)gr3 * K1 + k];
      } else {
        int kk = k - K1;
        v.x = A2[(size_t)gr0 * K2 + kk]; v.y = A2[(size_t)gr1 * K2 + kk];
        v.z = A2[(size_t)gr2 * K2 + kk]; v.w = A2[(size_t)gr3 * K2 + kk];
      }
    } else {
      v.x = A1[(size_t)gr0 * K1 + k]; v.y = A1[(size_t)gr1 * K1 + k];
      v.z = A1[(size_t)gr2 * K1 + k]; v.w = A1[(size_t)gr3 * K1 + k];
    }
    *(float4*)&Xs[k * ROWS + (r0 ^ ((k & 7) << 2))] = v;
  }
  __syncthreads();

  const int cg = tid % (DC / 4);
  const int rg = tid / (DC / 4);
  const int c0 = cg * 4, r0 = rg * 4;
  float acc[4][4] = {};
#pragma unroll 8
  for (int k = 0; k < K; ++k) {
    float4 wv = *(const float4*)&Ws[k * DC + c0];
    float4 xv = *(const float4*)&Xs[k * ROWS + (r0 ^ ((k & 7) << 2))];
    float xr[4] = {xv.x, xv.y, xv.z, xv.w};
    float wr[4] = {wv.x, wv.y, wv.z, wv.w};
#pragma unroll
    for (int i = 0; i < 4; ++i)
#pragma unroll
      for (int j = 0; j < 4; ++j) acc[i][j] = fmaf(xr[i], wr[j], acc[i][j]);
  }

#pragma unroll
  for (int i = 0; i < 4; ++i) {
    int grow = row0 + r0 + i;
    if (grow < NN) {
      float s = 1.0f;
      if (PRESCALE) s = dinv[grow];
      float o[4];
#pragma unroll
      for (int j = 0; j < 4; ++j) o[j] = acc[i][j] * s;
      if (BIAS) {
        float4 bv = *(const float4*)&bias[c0];
        o[0] += bv.x; o[1] += bv.y; o[2] += bv.z; o[3] += bv.w;
      }
      if (ACT == 1) {
#pragma unroll
        for (int j = 0; j < 4; ++j) o[j] = fmaxf(o[j], 0.0f);
      } else if (ACT == 2) {
#pragma unroll
        for (int j = 0; j < 4; ++j) o[j] = 1.0f / (1.0f + __expf(-o[j]));
      }
      float4 ov = {o[0], o[1], o[2], o[3]};
      *(float4*)&C[(size_t)grow * DC + c0] = ov;
    }
  }
}

// ---------------- aggregation (bf16 input rows, f32 accum/output) ----------------

template <int D, int ACT>
__global__ __launch_bounds__(256) void agg_k(const uint4* __restrict__ t, const int* __restrict__ rowstart,
                                             const int* __restrict__ cnt, const int* __restrict__ csr,
                                             const float* __restrict__ dinv, const float* __restrict__ bias,
                                             float* __restrict__ out) {
  constexpr int LPN = D / 8;
  int node = blockIdx.x * (256 / LPN) + threadIdx.x / LPN;
  int lane = threadIdx.x % LPN;
  if (node >= NN) return;

  float acc[8];
  uint4 sv = t[(size_t)node * LPN + lane];
  {
    uint_t u[4] = {sv.x, sv.y, sv.z, sv.w};
#pragma unroll
    for (int q = 0; q < 4; ++q) {
      acc[2 * q]     = __uint_as_float(u[q] << 16);
      acc[2 * q + 1] = __uint_as_float(u[q] & 0xffff0000u);
    }
  }
  int s = rowstart[node];
  int c = cnt[node];
  for (int j = 0; j < c; ++j) {
    int sn = csr[s + j];
    uint4 v = t[(size_t)sn * LPN + lane];
    uint_t u[4] = {v.x, v.y, v.z, v.w};
#pragma unroll
    for (int q = 0; q < 4; ++q) {
      acc[2 * q]     += __uint_as_float(u[q] << 16);
      acc[2 * q + 1] += __uint_as_float(u[q] & 0xffff0000u);
    }
  }
  float dv = dinv[node];
  float o[8];
#pragma unroll
  for (int q = 0; q < 8; ++q) {
    o[q] = acc[q] * dv + bias[lane * 8 + q];
    if (ACT == 1) o[q] = fmaxf(o[q], 0.0f);
  }
  size_t base = (size_t)node * D + lane * 8;
  float4 o0 = {o[0], o[1], o[2], o[3]};
  float4 o1 = {o[4], o[5], o[6], o[7]};
  *(float4*)&out[base] = o0;
  *(float4*)&out[base + 4] = o1;
}

// ---------------- launch ----------------

extern "C" void kernel_launch(void* const* d_in, const int* in_sizes, int n_in,
                              void* d_out, int out_size, void* d_ws, size_t ws_size,
                              hipStream_t stream) {
  const float* x  = (const float*)d_in[0];
  const float* y  = (const float*)d_in[1];
  const int* ei   = (const int*)d_in[2];
  const float* Wg1 = (const float*)d_in[3];
  const float* bg1 = (const float*)d_in[4];
  const float* Wg2 = (const float*)d_in[5];
  const float* bg2 = (const float*)d_in[6];
  const float* Wl  = (const float*)d_in[7];
  const float* bl  = (const float*)d_in[8];
  const float* Wf  = (const float*)d_in[9];
  const float* bf  = (const float*)d_in[10];
  float* out = (float*)d_out;

  char* ws = (char*)d_ws;
  size_t off = 0;
  auto alloc = [&](size_t bytes) { void* p = ws + off; off += (bytes + 511) & ~(size_t)511; return p; };
  int* cnt      = (int*)alloc((size_t)NN * 4);
  int* rowstart = (int*)alloc((size_t)NN * 4);
  int* blocksum = (int*)alloc(512);
  float* dinv   = (float*)alloc((size_t)NN * 4);
  int* csr      = (int*)alloc((size_t)NE * 4);
  int* bcnt     = (int*)alloc((size_t)NB * 4);
  uint_t* pairs = (uint_t*)alloc((size_t)NB * BCAP * 4);
  ushort_t* Tb  = (ushort_t*)alloc((size_t)NN * 128 * 2);  // bf16 GEMM->agg (feature); aliases XL0 later
  float* H      = (float*)alloc((size_t)NN * 128 * 4);     // f32 agg output / GEMM input
  ushort_t* Ub  = (ushort_t*)alloc((size_t)NN * 64 * 2);   // bf16 GEMM->agg (label)
  float* XL1    = (float*)alloc((size_t)NN * 64 * 4);
  ushort_t* G1h = (ushort_t*)alloc(128 * 128 * 2);
  ushort_t* G1l = (ushort_t*)alloc(128 * 128 * 2);
  ushort_t* G2h = (ushort_t*)alloc(128 * 128 * 2);
  ushort_t* G2l = (ushort_t*)alloc(128 * 128 * 2);
  ushort_t* Lh  = (ushort_t*)alloc(10 * 64 * 64 * 2);
  ushort_t* Ll  = (ushort_t*)alloc(10 * 64 * 64 * 2);
  float* XL0 = (float*)Tb;   // 25.6MB, exactly NN*64*4

  const int* esrc = ei;
  const int* edst = ei + NE;

  wprep_k<<<288, 256, 0, stream>>>(Wg1, Wg2, Wl, G1h, G1l, G2h, G2l, Lh, Ll);
  hipMemsetAsync(bcnt, 0, (size_t)NB * 4, stream);
  bucket_k<<<NE / 256, 256, 0, stream>>>(esrc, edst, bcnt, pairs);
  count2_k<<<NB, 256, 0, stream>>>(bcnt, pairs, cnt);
  dinv_k<<<(NN + 255) / 256, 256, 0, stream>>>(cnt, dinv);
  scan1<<<98, 1024, 0, stream>>>(cnt, rowstart, blocksum);
  scan2<<<1, 1, 0, stream>>>(blocksum, 98);
  scan3<<<98, 1024, 0, stream>>>(rowstart, blocksum);
  fill2_k<<<NB, 256, 0, stream>>>(bcnt, pairs, rowstart, csr);

  // feature branch
  mgemm_k<128, 128><<<(NN + 63) / 64, 256, 0, stream>>>(x, G1h, G1l, dinv, Tb);
  agg_k<128, 1><<<NN / 16, 256, 0, stream>>>((const uint4*)Tb, rowstart, cnt, csr, dinv, bg1, H);
  mgemm_k<128, 128><<<(NN + 63) / 64, 256, 0, stream>>>(H, G2h, G2l, dinv, Tb);
  agg_k<128, 0><<<NN / 16, 256, 0, stream>>>((const uint4*)Tb, rowstart, cnt, csr, dinv, bg2, H);

  // label branch: 10 layers, relu except last
  const float* xl = y;
  for (int j = 0; j < 10; ++j) {
    mgemm_k<64, 64><<<(NN + 63) / 64, 256, 0, stream>>>(xl, Lh + (size_t)j * 4096, Ll + (size_t)j * 4096, dinv, Ub);
    float* nxt = (j & 1) ? XL1 : XL0;
    if (j < 9)
      agg_k<64, 1><<<NN / 32, 256, 0, stream>>>((const uint4*)Ub, rowstart, cnt, csr, dinv, bl + (size_t)j * 64, nxt);
    else
      agg_k<64, 0><<<NN / 32, 256, 0, stream>>>((const uint4*)Ub, rowstart, cnt, csr, dinv, bl + (size_t)j * 64, nxt);
    xl = nxt;
  }

  // fused head: sigmoid([h2 | xl] @ Wf + bf), xl ended in XL1
  gemm_k<128, 64, 64, 64, 2, false, true><<<(NN + 63) / 64, 256, 0, stream>>>(H, XL1, Wf, bf, dinv, out);
}

// Round 4
// 964.237 us; speedup vs baseline: 1.3635x; 1.3635x over previous
//
#include <hip/hip_runtime.h>
#include <math.h>

#define NN 100000
#define NE 1600000
#define NB 782      // dst buckets of 128 nodes
#define BCAP 3072   // bucket capacity (mean ~2046, 22 sigma safe)
#define BKBLK 128   // blocks in bucket build
#define BKCHUNK (NE / BKBLK)  // 12500 edges per block

typedef unsigned short ushort_t;
typedef unsigned int uint_t;
typedef __attribute__((ext_vector_type(8))) short bf16x8;
typedef __attribute__((ext_vector_type(8))) unsigned short u16x8;
typedef __attribute__((ext_vector_type(4))) float f32x4;

__device__ __forceinline__ ushort_t f2bf(float f) {
  uint_t u = __float_as_uint(f);
  u = (u + 0x7fffu + ((u >> 16) & 1u)) >> 16;   // round-to-nearest-even
  return (ushort_t)u;
}
__device__ __forceinline__ float bf2f(ushort_t h) {
  return __uint_as_float((uint_t)h << 16);
}

// ---------------- setup: bucketed CSR build (histogram + reserve + write) ----------------

__global__ __launch_bounds__(512) void bucketA_k(const int* __restrict__ src, const int* __restrict__ dst,
                                                 int* __restrict__ bcnt, uint_t* __restrict__ pairs) {
  __shared__ int h[NB];
  const int t = threadIdx.x;
  const int e0 = blockIdx.x * BKCHUNK;
  for (int b = t; b < NB; b += 512) h[b] = 0;
  __syncthreads();
  // phase 1: LDS histogram of this block's chunk
  for (int i = t; i < BKCHUNK; i += 512) atomicAdd(&h[dst[e0 + i] >> 7], 1);
  __syncthreads();
  // phase 2: reserve a contiguous slice per bucket (one global atomic per (block,bucket))
  for (int b = t; b < NB; b += 512) h[b] = atomicAdd(&bcnt[b], h[b]);
  __syncthreads();
  // phase 3: write pairs into reserved slices (LDS cursor starts at reserved base)
  for (int i = t; i < BKCHUNK; i += 512) {
    int s = src[e0 + i], d = dst[e0 + i];
    int b = d >> 7;
    int pos = atomicAdd(&h[b], 1);
    if (pos < BCAP) pairs[b * BCAP + pos] = ((uint_t)s << 7) | (uint_t)(d & 127);
  }
}

__global__ __launch_bounds__(256) void count2_k(const int* __restrict__ bcnt, const uint_t* __restrict__ pairs,
                                                int* __restrict__ cnt) {
  __shared__ int c[128];
  int b = blockIdx.x, t = threadIdx.x;
  if (t < 128) c[t] = 0;
  __syncthreads();
  int n = min(bcnt[b], BCAP);
  for (int i = t; i < n; i += 256) atomicAdd(&c[pairs[b * BCAP + i] & 127], 1);
  __syncthreads();
  if (t < 128) {
    int node = b * 128 + t;
    if (node < NN) cnt[node] = c[t];
  }
}

__global__ __launch_bounds__(256) void dinv_k(const int* __restrict__ cnt, float* __restrict__ dinv) {
  int i = blockIdx.x * 256 + threadIdx.x;
  if (i < NN) dinv[i] = rsqrtf((float)(cnt[i] + 1));  // +1 self-loop; always > 0
}

__global__ __launch_bounds__(1024) void scan1(const int* __restrict__ cnt, int* __restrict__ rowstart,
                                              int* __restrict__ blocksum) {
  __shared__ int s[1024];
  int t = threadIdx.x;
  int i = blockIdx.x * 1024 + t;
  int v = (i < NN) ? cnt[i] : 0;
  s[t] = v;
  __syncthreads();
  for (int off = 1; off < 1024; off <<= 1) {
    int add = (t >= off) ? s[t - off] : 0;
    __syncthreads();
    s[t] += add;
    __syncthreads();
  }
  if (i < NN) rowstart[i] = s[t] - v;   // exclusive
  if (t == 1023) blocksum[blockIdx.x] = s[1023];
}

__global__ void scan2(int* blocksum, int nb) {
  if (threadIdx.x == 0 && blockIdx.x == 0) {
    int acc = 0;
    for (int b = 0; b < nb; ++b) { int v = blocksum[b]; blocksum[b] = acc; acc += v; }
  }
}

__global__ __launch_bounds__(1024) void scan3(int* __restrict__ rowstart, const int* __restrict__ blocksum) {
  int i = blockIdx.x * 1024 + threadIdx.x;
  if (i < NN) rowstart[i] += blocksum[blockIdx.x];
}

__global__ __launch_bounds__(256) void fill2_k(const int* __restrict__ bcnt, const uint_t* __restrict__ pairs,
                                               const int* __restrict__ rowstart, int* __restrict__ csr) {
  __shared__ int cur[128];
  int b = blockIdx.x, t = threadIdx.x;
  if (t < 128) cur[t] = 0;
  __syncthreads();
  int n = min(bcnt[b], BCAP);
  for (int i = t; i < n; i += 256) {
    uint_t p = pairs[b * BCAP + i];
    int lo = p & 127;
    int pos = rowstart[b * 128 + lo] + atomicAdd(&cur[lo], 1);
    csr[pos] = (int)(p >> 7);
  }
}

// ---------------- weight prep: transpose + bf16 hi/lo split ----------------

__global__ __launch_bounds__(256) void wprep_k(const float* __restrict__ Wg1, const float* __restrict__ Wg2,
                                               const float* __restrict__ Wl,
                                               ushort_t* __restrict__ G1h, ushort_t* __restrict__ G1l,
                                               ushort_t* __restrict__ G2h, ushort_t* __restrict__ G2l,
                                               ushort_t* __restrict__ Lh, ushort_t* __restrict__ Ll) {
  int i = blockIdx.x * 256 + threadIdx.x;   // 0..73727
  float w;
  ushort_t *ph, *pl;
  size_t di;
  if (i < 16384) {           // Wg1 128x128
    int k = i >> 7, n = i & 127;
    w = Wg1[i]; di = (size_t)n * 128 + k; ph = G1h; pl = G1l;
  } else if (i < 32768) {    // Wg2 128x128
    int i2 = i - 16384;
    int k = i2 >> 7, n = i2 & 127;
    w = Wg2[i2]; di = (size_t)n * 128 + k; ph = G2h; pl = G2l;
  } else {                   // Wl 10 x 64x64
    int i2 = i - 32768;
    int j = i2 >> 12, r = i2 & 4095;
    int k = r >> 6, n = r & 63;
    w = Wl[i2]; di = (size_t)j * 4096 + n * 64 + k; ph = Lh; pl = Ll;
  }
  ushort_t h = f2bf(w);
  ph[di] = h;
  pl[di] = f2bf(w - bf2f(h));
}

// ---------------- MFMA GEMM (bf16x3 split ~ f32 accuracy) ----------------

template <int K, int DC>
__global__ __launch_bounds__(256) void mgemm_k(const float* __restrict__ A,
                                               const ushort_t* __restrict__ Wth, const ushort_t* __restrict__ Wtl,
                                               const float* __restrict__ dinv, ushort_t* __restrict__ C) {
  constexpr int NCH = K / 64;
  __shared__ ushort_t Ah[64 * 64], Al[64 * 64];
  __shared__ ushort_t Wh[DC * 64], Wl_[DC * 64];
  const int t = threadIdx.x;
  const int row0 = blockIdx.x * 64;
  const int w = t >> 6, l = t & 63;
  const int lr = l & 15, kh = l >> 4;

  f32x4 acc[DC / 16];
  const f32x4 zz = {0.f, 0.f, 0.f, 0.f};
#pragma unroll
  for (int ct = 0; ct < DC / 16; ++ct) acc[ct] = zz;

  for (int kc = 0; kc < NCH; ++kc) {
    if (kc) __syncthreads();
#pragma unroll
    for (int it = 0; it < 4; ++it) {
      int idx = t + it * 256;
      int row = idx >> 4, kq = idx & 15;
      int gr = min(row0 + row, NN - 1);
      float4 a = *(const float4*)&A[(size_t)gr * K + kc * 64 + kq * 4];
      ushort4 h, lo;
      h.x = f2bf(a.x); lo.x = f2bf(a.x - bf2f(h.x));
      h.y = f2bf(a.y); lo.y = f2bf(a.y - bf2f(h.y));
      h.z = f2bf(a.z); lo.z = f2bf(a.z - bf2f(h.z));
      h.w = f2bf(a.w); lo.w = f2bf(a.w - bf2f(h.w));
      int byt = (row * 128 + kq * 8) ^ ((row & 7) << 4);
      *(ushort4*)&Ah[byt >> 1] = h;
      *(ushort4*)&Al[byt >> 1] = lo;
    }
    for (int idx = t; idx < DC * 8; idx += 256) {
      int n = idx >> 3, kq = idx & 7;
      u16x8 hv = *(const u16x8*)&Wth[(size_t)n * K + kc * 64 + kq * 8];
      u16x8 lv = *(const u16x8*)&Wtl[(size_t)n * K + kc * 64 + kq * 8];
      int byt = (n * 128 + kq * 16) ^ ((n & 7) << 4);
      *(u16x8*)&Wh[byt >> 1] = hv;
      *(u16x8*)&Wl_[byt >> 1] = lv;
    }
    __syncthreads();
#pragma unroll
    for (int kc2 = 0; kc2 < 2; ++kc2) {
      int arow = w * 16 + lr;
      int ab = (arow * 128 + kc2 * 64 + kh * 16) ^ ((arow & 7) << 4);
      bf16x8 ah = *(const bf16x8*)&Ah[ab >> 1];
      bf16x8 al = *(const bf16x8*)&Al[ab >> 1];
#pragma unroll
      for (int ct = 0; ct < DC / 16; ++ct) {
        int n = ct * 16 + lr;
        int bb = (n * 128 + kc2 * 64 + kh * 16) ^ ((n & 7) << 4);
        bf16x8 bh = *(const bf16x8*)&Wh[bb >> 1];
        bf16x8 bl = *(const bf16x8*)&Wl_[bb >> 1];
        acc[ct] = __builtin_amdgcn_mfma_f32_16x16x32_bf16(al, bh, acc[ct], 0, 0, 0);
        acc[ct] = __builtin_amdgcn_mfma_f32_16x16x32_bf16(ah, bl, acc[ct], 0, 0, 0);
        acc[ct] = __builtin_amdgcn_mfma_f32_16x16x32_bf16(ah, bh, acc[ct], 0, 0, 0);
      }
    }
  }
  float dv[4];
#pragma unroll
  for (int r = 0; r < 4; ++r) {
    int grow = row0 + w * 16 + kh * 4 + r;
    dv[r] = (grow < NN) ? dinv[grow] : 0.0f;
  }
#pragma unroll
  for (int ct = 0; ct < DC / 16; ++ct) {
    int col = ct * 16 + lr;
#pragma unroll
    for (int r = 0; r < 4; ++r) {
      int grow = row0 + w * 16 + kh * 4 + r;
      if (grow < NN) C[(size_t)grow * DC + col] = f2bf(acc[ct][r] * dv[r]);
    }
  }
}

// ---------------- f32 VALU GEMM (head only) ----------------

template <int K1, int K2, int DC, int ROWS, int ACT, bool PRESCALE, bool BIAS>
__global__ __launch_bounds__(256) void gemm_k(const float* __restrict__ A1, const float* __restrict__ A2,
                                              const float* __restrict__ W, const float* __restrict__ bias,
                                              const float* __restrict__ dinv, float* __restrict__ C) {
  constexpr int K = K1 + K2;
  static_assert((DC / 4) * (ROWS / 4) == 256, "thread map");
  __shared__ float Ws[K * DC];
  __shared__ float Xs[K * ROWS];
  const int tid = threadIdx.x;
  const int row0 = blockIdx.x * ROWS;

  for (int idx = tid * 4; idx < K * DC; idx += 1024)
    *(float4*)&Ws[idx] = *(const float4*)&W[idx];

  for (int idx = tid; idx < K * (ROWS / 4); idx += 256) {
    int k = idx % K;
    int r0 = (idx / K) * 4;
    int g0 = row0 + r0;
    int gr0 = min(g0 + 0, NN - 1);
    int gr1 = min(g0 + 1, NN - 1);
    int gr2 = min(g0 + 2, NN - 1);
    int gr3 = min(g0 + 3, NN - 1);
    float4 v;
    if constexpr (K2 > 0) {
      if (k < K1) {
        v.x = A1[(size_t)gr0 * K1 + k]; v.y = A1[(size_t)gr1 * K1 + k];
        v.z = A1[(size_t)gr2 * K1 + k]; v.w = A1[(size_t)gr3 * K1 + k];
      } else {
        int kk = k - K1;
        v.x = A2[(size_t)gr0 * K2 + kk]; v.y = A2[(size_t)gr1 * K2 + kk];
        v.z = A2[(size_t)gr2 * K2 + kk]; v.w = A2[(size_t)gr3 * K2 + kk];
      }
    } else {
      v.x = A1[(size_t)gr0 * K1 + k]; v.y = A1[(size_t)gr1 * K1 + k];
      v.z = A1[(size_t)gr2 * K1 + k]; v.w = A1[(size_t)gr3 * K1 + k];
    }
    *(float4*)&Xs[k * ROWS + (r0 ^ ((k & 7) << 2))] = v;
  }
  __syncthreads();

  const int cg = tid % (DC / 4);
  const int rg = tid / (DC / 4);
  const int c0 = cg * 4, r0 = rg * 4;
  float acc[4][4] = {};
#pragma unroll 8
  for (int k = 0; k < K; ++k) {
    float4 wv = *(const float4*)&Ws[k * DC + c0];
    float4 xv = *(const float4*)&Xs[k * ROWS + (r0 ^ ((k & 7) << 2))];
    float xr[4] = {xv.x, xv.y, xv.z, xv.w};
    float wr[4] = {wv.x, wv.y, wv.z, wv.w};
#pragma unroll
    for (int i = 0; i < 4; ++i)
#pragma unroll
      for (int j = 0; j < 4; ++j) acc[i][j] = fmaf(xr[i], wr[j], acc[i][j]);
  }

#pragma unroll
  for (int i = 0; i < 4; ++i) {
    int grow = row0 + r0 + i;
    if (grow < NN) {
      float s = 1.0f;
      if (PRESCALE) s = dinv[grow];
      float o[4];
#pragma unroll
      for (int j = 0; j < 4; ++j) o[j] = acc[i][j] * s;
      if (BIAS) {
        float4 bv = *(const float4*)&bias[c0];
        o[0] += bv.x; o[1] += bv.y; o[2] += bv.z; o[3] += bv.w;
      }
      if (ACT == 1) {
#pragma unroll
        for (int j = 0; j < 4; ++j) o[j] = fmaxf(o[j], 0.0f);
      } else if (ACT == 2) {
#pragma unroll
        for (int j = 0; j < 4; ++j) o[j] = 1.0f / (1.0f + __expf(-o[j]));
      }
      float4 ov = {o[0], o[1], o[2], o[3]};
      *(float4*)&C[(size_t)grow * DC + c0] = ov;
    }
  }
}

// ---------------- aggregation (bf16 input rows, f32 accum/output) ----------------

template <int D, int ACT>
__global__ __launch_bounds__(256) void agg_k(const uint4* __restrict__ t, const int* __restrict__ rowstart,
                                             const int* __restrict__ cnt, const int* __restrict__ csr,
                                             const float* __restrict__ dinv, const float* __restrict__ bias,
                                             float* __restrict__ out) {
  constexpr int LPN = D / 8;
  int node = blockIdx.x * (256 / LPN) + threadIdx.x / LPN;
  int lane = threadIdx.x % LPN;
  if (node >= NN) return;

  float acc[8];
  uint4 sv = t[(size_t)node * LPN + lane];
  {
    uint_t u[4] = {sv.x, sv.y, sv.z, sv.w};
#pragma unroll
    for (int q = 0; q < 4; ++q) {
      acc[2 * q]     = __uint_as_float(u[q] << 16);
      acc[2 * q + 1] = __uint_as_float(u[q] & 0xffff0000u);
    }
  }
  int s = rowstart[node];
  int c = cnt[node];
  for (int j = 0; j < c; ++j) {
    int sn = csr[s + j];
    uint4 v = t[(size_t)sn * LPN + lane];
    uint_t u[4] = {v.x, v.y, v.z, v.w};
#pragma unroll
    for (int q = 0; q < 4; ++q) {
      acc[2 * q]     += __uint_as_float(u[q] << 16);
      acc[2 * q + 1] += __uint_as_float(u[q] & 0xffff0000u);
    }
  }
  float dv = dinv[node];
  float o[8];
#pragma unroll
  for (int q = 0; q < 8; ++q) {
    o[q] = acc[q] * dv + bias[lane * 8 + q];
    if (ACT == 1) o[q] = fmaxf(o[q], 0.0f);
  }
  size_t base = (size_t)node * D + lane * 8;
  float4 o0 = {o[0], o[1], o[2], o[3]};
  float4 o1 = {o[4], o[5], o[6], o[7]};
  *(float4*)&out[base] = o0;
  *(float4*)&out[base + 4] = o1;
}

// ---------------- launch ----------------

extern "C" void kernel_launch(void* const* d_in, const int* in_sizes, int n_in,
                              void* d_out, int out_size, void* d_ws, size_t ws_size,
                              hipStream_t stream) {
  const float* x  = (const float*)d_in[0];
  const float* y  = (const float*)d_in[1];
  const int* ei   = (const int*)d_in[2];
  const float* Wg1 = (const float*)d_in[3];
  const float* bg1 = (const float*)d_in[4];
  const float* Wg2 = (const float*)d_in[5];
  const float* bg2 = (const float*)d_in[6];
  const float* Wl  = (const float*)d_in[7];
  const float* bl  = (const float*)d_in[8];
  const float* Wf  = (const float*)d_in[9];
  const float* bf  = (const float*)d_in[10];
  float* out = (float*)d_out;

  char* ws = (char*)d_ws;
  size_t off = 0;
  auto alloc = [&](size_t bytes) { void* p = ws + off; off += (bytes + 511) & ~(size_t)511; return p; };
  int* cnt      = (int*)alloc((size_t)NN * 4);
  int* rowstart = (int*)alloc((size_t)NN * 4);
  int* blocksum = (int*)alloc(512);
  float* dinv   = (float*)alloc((size_t)NN * 4);
  int* csr      = (int*)alloc((size_t)NE * 4);
  int* bcnt     = (int*)alloc((size_t)NB * 4);
  uint_t* pairs = (uint_t*)alloc((size_t)NB * BCAP * 4);
  ushort_t* Tb  = (ushort_t*)alloc((size_t)NN * 128 * 2);  // bf16 GEMM->agg (feature); aliases XL0 later
  float* H      = (float*)alloc((size_t)NN * 128 * 4);     // f32 agg output / GEMM input
  ushort_t* Ub  = (ushort_t*)alloc((size_t)NN * 64 * 2);   // bf16 GEMM->agg (label)
  float* XL1    = (float*)alloc((size_t)NN * 64 * 4);
  ushort_t* G1h = (ushort_t*)alloc(128 * 128 * 2);
  ushort_t* G1l = (ushort_t*)alloc(128 * 128 * 2);
  ushort_t* G2h = (ushort_t*)alloc(128 * 128 * 2);
  ushort_t* G2l = (ushort_t*)alloc(128 * 128 * 2);
  ushort_t* Lh  = (ushort_t*)alloc(10 * 64 * 64 * 2);
  ushort_t* Ll  = (ushort_t*)alloc(10 * 64 * 64 * 2);
  float* XL0 = (float*)Tb;   // 25.6MB, exactly NN*64*4

  const int* esrc = ei;
  const int* edst = ei + NE;

  wprep_k<<<288, 256, 0, stream>>>(Wg1, Wg2, Wl, G1h, G1l, G2h, G2l, Lh, Ll);
  hipMemsetAsync(bcnt, 0, (size_t)NB * 4, stream);
  bucketA_k<<<BKBLK, 512, 0, stream>>>(esrc, edst, bcnt, pairs);
  count2_k<<<NB, 256, 0, stream>>>(bcnt, pairs, cnt);
  dinv_k<<<(NN + 255) / 256, 256, 0, stream>>>(cnt, dinv);
  scan1<<<98, 1024, 0, stream>>>(cnt, rowstart, blocksum);
  scan2<<<1, 1, 0, stream>>>(blocksum, 98);
  scan3<<<98, 1024, 0, stream>>>(rowstart, blocksum);
  fill2_k<<<NB, 256, 0, stream>>>(bcnt, pairs, rowstart, csr);

  // feature branch
  mgemm_k<128, 128><<<(NN + 63) / 64, 256, 0, stream>>>(x, G1h, G1l, dinv, Tb);
  agg_k<128, 1><<<NN / 16, 256, 0, stream>>>((const uint4*)Tb, rowstart, cnt, csr, dinv, bg1, H);
  mgemm_k<128, 128><<<(NN + 63) / 64, 256, 0, stream>>>(H, G2h, G2l, dinv, Tb);
  agg_k<128, 0><<<NN / 16, 256, 0, stream>>>((const uint4*)Tb, rowstart, cnt, csr, dinv, bg2, H);

  // label branch: 10 layers, relu except last
  const float* xl = y;
  for (int j = 0; j < 10; ++j) {
    mgemm_k<64, 64><<<(NN + 63) / 64, 256, 0, stream>>>(xl, Lh + (size_t)j * 4096, Ll + (size_t)j * 4096, dinv, Ub);
    float* nxt = (j & 1) ? XL1 : XL0;
    if (j < 9)
      agg_k<64, 1><<<NN / 32, 256, 0, stream>>>((const uint4*)Ub, rowstart, cnt, csr, dinv, bl + (size_t)j * 64, nxt);
    else
      agg_k<64, 0><<<NN / 32, 256, 0, stream>>>((const uint4*)Ub, rowstart, cnt, csr, dinv, bl + (size_t)j * 64, nxt);
    xl = nxt;
  }

  // fused head: sigmoid([h2 | xl] @ Wf + bf), xl ended in XL1
  gemm_k<128, 64, 64, 64, 2, false, true><<<(NN + 63) / 64, 256, 0, stream>>>(H, XL1, Wf, bf, dinv, out);
}